// Round 7
// baseline (924.815 us; speedup 1.0000x reference)
//
#include <hip/hip_runtime.h>
#include <math.h>

static constexpr int H = 256, W = 256, HW = H * W;

typedef __attribute__((ext_vector_type(8))) _Float16 half8v;  // 16B
typedef __attribute__((ext_vector_type(4))) _Float16 half4v;  // 8B
typedef __attribute__((ext_vector_type(4))) float  float4v;   // MFMA acc

// ---------- activations ----------
__device__ __forceinline__ float gelu_f(float v) {
  return 0.5f * v * (1.0f + erff(v * 0.70710678118654752440f));
}
template<int ACT>
__device__ __forceinline__ float apply_act(float v) {
  if constexpr (ACT == 1) return v >= 0.f ? v : 0.1f * v;   // LeakyReLU(0.1)
  if constexpr (ACT == 2) return gelu_f(v);
  return v;
}

// ---------- pack: NCHW f32 -> NHWC f16 hi + scaled lo ----------
template<int C>
__global__ __launch_bounds__(256)
void pack_k(const float* __restrict__ in, _Float16* __restrict__ hi, _Float16* __restrict__ lo)
{
  const int p = blockIdx.x * 256 + threadIdx.x;
  const int b = blockIdx.y;
  const float* ip = in + (size_t)b * C * HW + p;
  __attribute__((aligned(16))) _Float16 hv[C], lv[C];
  #pragma unroll
  for (int c = 0; c < C; ++c) {
    float v = ip[(size_t)c * HW];
    _Float16 h = (_Float16)v;
    hv[c] = h;
    lv[c] = (_Float16)((v - (float)h) * 2048.0f);
  }
  size_t ob = ((size_t)b * HW + p) * C;
  #pragma unroll
  for (int j = 0; j < C / 8; ++j) {
    *(half8v*)&hi[ob + j * 8] = *(half8v*)&hv[j * 8];
    *(half8v*)&lo[ob + j * 8] = *(half8v*)&lv[j * 8];
  }
}

// ---------- weight prep: [OC][CIN][3][3] f32 -> [tap][OC][CIN] f16 hi + scaled lo ----------
__global__ __launch_bounds__(256)
void prep_w_k(const float* __restrict__ w, _Float16* __restrict__ hi,
              _Float16* __restrict__ lo, int OC, int CIN)
{
  int tid = blockIdx.x * 256 + threadIdx.x;
  if (tid >= OC * CIN * 9) return;
  int ci = tid % CIN; int r = tid / CIN; int oc = r % OC; int tap = r / OC;
  float v = w[((size_t)oc * CIN + ci) * 9 + tap];
  _Float16 h = (_Float16)v;
  hi[tid] = h;
  lo[tid] = (_Float16)((v - (float)h) * 2048.0f);
}

// ---------- 3x3 conv, f16 MFMA split-3; NHWC f16 hi/lo input, LDS+geometry as verified r5/r6 ----------
// OMODE: 0 = NCHW f32 out, 1 = NHWC f16 hi/lo out, 2 = NHWC f32 out.
// Inputs: channels [0,cin0) from (iH0,iL0) with record stride cin0; rest from (iH1,iL1).
template<int CIN, int ACT, int OMODE>
__global__ __launch_bounds__(256)
void conv3x3_mfma_k(const _Float16* __restrict__ iH0, const _Float16* __restrict__ iL0,
                    const _Float16* __restrict__ iH1, const _Float16* __restrict__ iL1, int cin0,
                    const _Float16* __restrict__ wHi, const _Float16* __restrict__ wLo,
                    const float* __restrict__ bias,
                    float* __restrict__ outF, _Float16* __restrict__ oH, _Float16* __restrict__ oL,
                    int OC)
{
  __shared__ _Float16 sB[6 * 66 * 72];   // 57,024 B

  const int l  = threadIdx.x & 63;
  const int wv = threadIdx.x >> 6;
  const int nOc = OC >> 5;
  const int b   = blockIdx.x / nOc;
  const int oc0 = (blockIdx.x % nOc) * 32;
  const int x0  = blockIdx.y * 64;
  const int y0  = blockIdx.z * 4;

  float4v accP[2][4], accQ[2][4];
  #pragma unroll
  for (int of = 0; of < 2; ++of)
    #pragma unroll
    for (int f = 0; f < 4; ++f) {
      accP[of][f] = (float4v){0.f, 0.f, 0.f, 0.f};
      accQ[of][f] = (float4v){0.f, 0.f, 0.f, 0.f};
    }

  const int gx_m  = x0 + l - 1;
  const bool vx_m = (gx_m >= 0 && gx_m < W);
  const int gxc_m = gx_m < 0 ? 0 : (gx_m >= W ? W - 1 : gx_m);
  const int gx_e  = gx_m + 64;
  const bool vx_e = (l < 2) && (gx_e < W);
  const int gxc_e = gx_e >= W ? W - 1 : gx_e;

  const int k8  = (l >> 4) * 8;
  const int ocl = l & 15;

  #pragma unroll 1
  for (int cc = 0; cc < CIN; cc += 32) {
    __syncthreads();
    // ---- stage: 24 tasks (6 rows x 4 granules of 8 ci); pure 16B copies ----
    #pragma unroll 1
    for (int t = wv; t < 24; t += 4) {
      int r = t >> 2, g = t & 3;
      int gy = y0 + r - 1;
      bool vy = (gy >= 0 && gy < H);
      int gyc = gy < 0 ? 0 : (gy >= H ? H - 1 : gy);
      int ci0 = cc + g * 8;
      const _Float16 *sh, *sl; int rec, co;
      if (ci0 < cin0) { sh = iH0; sl = iL0; rec = cin0;        co = ci0; }
      else            { sh = iH1; sl = iL1; rec = CIN - cin0;  co = ci0 - cin0; }
      size_t rowb = ((size_t)b * HW + (size_t)gyc * W) * rec + co;

      half8v h8, l8;
      if (vy && vx_m) {
        h8 = *(const half8v*)&sh[rowb + (size_t)gxc_m * rec];
        l8 = *(const half8v*)&sl[rowb + (size_t)gxc_m * rec];
      } else {
        #pragma unroll
        for (int i = 0; i < 8; ++i) { h8[i] = (_Float16)0; l8[i] = (_Float16)0; }
      }
      int basei = (r * 66 + l) * 72 + g * 8;
      *(half8v*)&sB[basei]      = h8;
      *(half8v*)&sB[basei + 32] = l8;
      if (l < 2) {
        half8v h8e, l8e;
        if (vy && vx_e) {
          h8e = *(const half8v*)&sh[rowb + (size_t)gxc_e * rec];
          l8e = *(const half8v*)&sl[rowb + (size_t)gxc_e * rec];
        } else {
          #pragma unroll
          for (int i = 0; i < 8; ++i) { h8e[i] = (_Float16)0; l8e[i] = (_Float16)0; }
        }
        int be = (r * 66 + 64 + l) * 72 + g * 8;
        *(half8v*)&sB[be]      = h8e;
        *(half8v*)&sB[be + 32] = l8e;
      }
    }
    __syncthreads();

    #pragma unroll 1
    for (int tap = 0; tap < 9; ++tap) {
      const int dy = tap / 3, dx = tap - 3 * (tap / 3);
      const _Float16* hp = wHi + ((size_t)tap * OC + oc0 + ocl) * CIN + cc + k8;
      const _Float16* lp = wLo + ((size_t)tap * OC + oc0 + ocl) * CIN + cc + k8;
      half8v ah0 = *(const half8v*)hp;
      half8v ah1 = *(const half8v*)(hp + (size_t)16 * CIN);
      half8v aq0 = *(const half8v*)lp;
      half8v aq1 = *(const half8v*)(lp + (size_t)16 * CIN);
      const int brow = ((wv + dy) * 66 + ocl + dx) * 72 + k8;
      #pragma unroll
      for (int f = 0; f < 4; ++f) {
        half8v bh = *(const half8v*)&sB[brow + f * 16 * 72];
        half8v bq = *(const half8v*)&sB[brow + f * 16 * 72 + 32];
        accP[0][f] = __builtin_amdgcn_mfma_f32_16x16x32_f16(ah0, bh, accP[0][f], 0, 0, 0);
        accQ[0][f] = __builtin_amdgcn_mfma_f32_16x16x32_f16(ah0, bq, accQ[0][f], 0, 0, 0);
        accQ[0][f] = __builtin_amdgcn_mfma_f32_16x16x32_f16(aq0, bh, accQ[0][f], 0, 0, 0);
        accP[1][f] = __builtin_amdgcn_mfma_f32_16x16x32_f16(ah1, bh, accP[1][f], 0, 0, 0);
        accQ[1][f] = __builtin_amdgcn_mfma_f32_16x16x32_f16(ah1, bq, accQ[1][f], 0, 0, 0);
        accQ[1][f] = __builtin_amdgcn_mfma_f32_16x16x32_f16(aq1, bh, accQ[1][f], 0, 0, 0);
      }
    }
  }

  // ---- epilogue: D col=l&15 (px), row=(l>>4)*4+reg (oc) ----
  #pragma unroll
  for (int of = 0; of < 2; ++of)
    #pragma unroll
    for (int f = 0; f < 4; ++f) {
      const int px  = x0 + f * 16 + ocl;
      const int occ = oc0 + of * 16 + (l >> 4) * 4;
      if constexpr (OMODE == 0) {
        #pragma unroll
        for (int r = 0; r < 4; ++r) {
          float bv = bias ? bias[occ + r] : 0.f;
          float vv = accP[of][f][r] + accQ[of][f][r] * (1.0f / 2048.0f) + bv;
          outF[((size_t)(b * OC + occ + r) * H + (y0 + wv)) * W + px] = apply_act<ACT>(vv);
        }
      } else if constexpr (OMODE == 1) {
        __attribute__((aligned(8))) _Float16 hv[4], lv[4];
        #pragma unroll
        for (int r = 0; r < 4; ++r) {
          float bv = bias ? bias[occ + r] : 0.f;
          float vv = apply_act<ACT>(accP[of][f][r] + accQ[of][f][r] * (1.0f / 2048.0f) + bv);
          _Float16 h = (_Float16)vv;
          hv[r] = h;
          lv[r] = (_Float16)((vv - (float)h) * 2048.0f);
        }
        size_t ob = ((size_t)b * HW + (size_t)(y0 + wv) * W + px) * OC + occ;
        *(half4v*)&oH[ob] = *(half4v*)&hv[0];
        *(half4v*)&oL[ob] = *(half4v*)&lv[0];
      } else {
        float4 v4;
        #pragma unroll
        for (int r = 0; r < 4; ++r) {
          float bv = bias ? bias[occ + r] : 0.f;
          float vv = apply_act<ACT>(accP[of][f][r] + accQ[of][f][r] * (1.0f / 2048.0f) + bv);
          ((float*)&v4)[r] = vv;
        }
        *(float4*)&outF[((size_t)b * HW + (size_t)(y0 + wv) * W + px) * OC + occ] = v4;
      }
    }
}

// ---------- 1x1 conv: NHWC f32 in -> NHWC f16 hi/lo out; LDS weights, 4 px/thread ----------
template<int CIN, int OCB, int ACT>
__global__ __launch_bounds__(256)
void conv1x1_nhwc_k(const float* __restrict__ in, const float* __restrict__ w,
                    _Float16* __restrict__ oH, _Float16* __restrict__ oL, int OC)
{
  __shared__ __align__(16) float sW[OCB][CIN];
  const int b   = blockIdx.y;
  const int oc0 = blockIdx.z * OCB;
  for (int t = threadIdx.x; t < OCB * CIN; t += 256)
    sW[t / CIN][t % CIN] = w[(size_t)(oc0 + t / CIN) * CIN + (t % CIN)];
  __syncthreads();

  const int pb = blockIdx.x * 1024 + threadIdx.x;    // 4 px at stride 256
  float acc[OCB][4];
  #pragma unroll
  for (int o = 0; o < OCB; ++o)
    #pragma unroll
    for (int i = 0; i < 4; ++i) acc[o][i] = 0.f;

  #pragma unroll 1
  for (int c0 = 0; c0 < CIN; c0 += 8) {
    float v[4][8];
    #pragma unroll
    for (int i = 0; i < 4; ++i) {
      const float* ip = in + ((size_t)b * HW + pb + i * 256) * CIN + c0;
      float4 a = *(const float4*)ip;
      float4 c = *(const float4*)(ip + 4);
      v[i][0]=a.x; v[i][1]=a.y; v[i][2]=a.z; v[i][3]=a.w;
      v[i][4]=c.x; v[i][5]=c.y; v[i][6]=c.z; v[i][7]=c.w;
    }
    #pragma unroll
    for (int o = 0; o < OCB; ++o) {
      const float4 w0 = *(const float4*)&sW[o][c0];
      const float4 w1 = *(const float4*)&sW[o][c0 + 4];
      #pragma unroll
      for (int i = 0; i < 4; ++i) {
        acc[o][i] += v[i][0]*w0.x + v[i][1]*w0.y + v[i][2]*w0.z + v[i][3]*w0.w
                   + v[i][4]*w1.x + v[i][5]*w1.y + v[i][6]*w1.z + v[i][7]*w1.w;
      }
    }
  }
  #pragma unroll
  for (int i = 0; i < 4; ++i) {
    __attribute__((aligned(16))) _Float16 hv[OCB], lv[OCB];
    #pragma unroll
    for (int o = 0; o < OCB; ++o) {
      float vv = apply_act<ACT>(acc[o][i]);
      _Float16 h = (_Float16)vv;
      hv[o] = h;
      lv[o] = (_Float16)((vv - (float)h) * 2048.0f);
    }
    size_t ob = ((size_t)b * HW + pb + i * 256) * OC + oc0;
    #pragma unroll
    for (int j = 0; j < OCB / 8; ++j) {
      *(half8v*)&oH[ob + j * 8] = *(half8v*)&hv[j * 8];
      *(half8v*)&oL[ob + j * 8] = *(half8v*)&lv[j * 8];
    }
  }
}

// ---------- corr + top-3 (jax tie-break: lower index wins); warp NCHW f32 ----------
__global__ __launch_bounds__(256)
void corr_topk_k(const float* __restrict__ warp, const float* __restrict__ x,
                 int* __restrict__ idxo)
{
  const int p = blockIdx.x * 256 + threadIdx.x;
  const int b = blockIdx.y;
  float corr[9];
  #pragma unroll
  for (int o = 0; o < 9; ++o) corr[o] = 0.f;
  #pragma unroll 2
  for (int c = 0; c < 32; ++c) {
    float xv = x[((size_t)b * 32 + c) * HW + p];
    const float* wp = warp + ((size_t)b * 288 + (size_t)c * 9) * HW + p;
    #pragma unroll
    for (int o = 0; o < 9; ++o) corr[o] += wp[(size_t)o * HW] * xv;
  }
  unsigned mask = 0;
  int packed = 0;
  #pragma unroll
  for (int t = 0; t < 3; ++t) {
    float best = -INFINITY; int bi = 0;
    #pragma unroll
    for (int o = 0; o < 9; ++o) {
      bool take = (((mask >> o) & 1u) == 0u) && (corr[o] > best);
      best = take ? corr[o] : best;
      bi   = take ? o       : bi;
    }
    mask   |= 1u << bi;
    packed |= bi << (4 * t);
  }
  idxo[(size_t)b * HW + p] = packed;
}

// ---------- gather selected warps + 3x3 conv with w_sel; out NHWC f16 hi/lo ----------
__global__ __launch_bounds__(256)
void selconv_k(const float* __restrict__ warp, const int* __restrict__ idxp,
               const float* __restrict__ wsel, const float* __restrict__ bsel,
               _Float16* __restrict__ oH, _Float16* __restrict__ oL)
{
  const int tx = threadIdx.x & 31, ty = threadIdx.x >> 5;
  const int px = blockIdx.x * 32 + tx;
  const int py = blockIdx.y * 8 + ty;
  const int b  = blockIdx.z;

  int  nidx[9];
  bool nval[9];
  int  qoff[9];
  #pragma unroll
  for (int kh = 0; kh < 3; ++kh)
    #pragma unroll
    for (int kw = 0; kw < 3; ++kw) {
      int k = kh * 3 + kw;
      int qy = py + kh - 1, qx = px + kw - 1;
      nval[k] = (qy >= 0 && qy < H && qx >= 0 && qx < W);
      qoff[k] = qy * W + qx;
      nidx[k] = nval[k] ? idxp[(size_t)b * HW + qoff[k]] : 0;
    }

  float ws27[27];
  #pragma unroll
  for (int i = 0; i < 27; ++i) ws27[i] = wsel[i];
  const float bs = bsel[0];

  float arr[32];
  #pragma unroll 1
  for (int c = 0; c < 32; ++c) {
    float acc = bs;
    const float* wb = warp + ((size_t)b * 288 + (size_t)c * 9) * HW;
    #pragma unroll
    for (int k = 0; k < 9; ++k) {
      if (nval[k]) {
        int pk = nidx[k];
        #pragma unroll
        for (int t = 0; t < 3; ++t) {
          int o = (pk >> (4 * t)) & 15;
          acc += ws27[t * 9 + k] * wb[(size_t)o * HW + qoff[k]];
        }
      }
    }
    arr[c] = acc;
  }

  __attribute__((aligned(16))) _Float16 hv[32], lv[32];
  #pragma unroll
  for (int c = 0; c < 32; ++c) {
    _Float16 h = (_Float16)arr[c];
    hv[c] = h;
    lv[c] = (_Float16)((arr[c] - (float)h) * 2048.0f);
  }
  size_t ob = ((size_t)b * HW + (size_t)py * W + px) * 32;
  #pragma unroll
  for (int j = 0; j < 4; ++j) {
    *(half8v*)&oH[ob + j * 8] = *(half8v*)&hv[j * 8];
    *(half8v*)&oL[ob + j * 8] = *(half8v*)&lv[j * 8];
  }
}

// ---------- launch ----------
extern "C" void kernel_launch(void* const* d_in, const int* in_sizes, int n_in,
                              void* d_out, int out_size, void* d_ws, size_t ws_size,
                              hipStream_t stream) {
  const float* x      = (const float*)d_in[0];
  const float* key    = (const float*)d_in[1];
  const float* w_off1 = (const float*)d_in[2];
  const float* b_off1 = (const float*)d_in[3];
  const float* w_off2 = (const float*)d_in[4];
  const float* b_off2 = (const float*)d_in[5];
  const float* w_dcn  = (const float*)d_in[6];
  const float* b_dcn  = (const float*)d_in[7];
  const float* w_sel  = (const float*)d_in[8];
  const float* b_sel  = (const float*)d_in[9];
  const float* w_t1   = (const float*)d_in[10];
  const float* w_t2   = (const float*)d_in[11];
  const float* w_t3   = (const float*)d_in[12];
  const float* w_t4   = (const float*)d_in[13];
  const float* w_t5   = (const float*)d_in[14];

  // ---- workspace layout (peak 185.2 MB; <= 185.8 MB proven safe in r5/r6) ----
  char* ws = (char*)d_ws;
  float* warp = (float*)(ws);                                // [2,288,HW] f32 NCHW, 144 MiB
  // pre-dcn scratch inside warp region (dead before dcn writes):
  _Float16* xH  = (_Float16*)(ws);                           // 8 MiB
  _Float16* xL  = (_Float16*)(ws + 8388608);
  _Float16* o1H = (_Float16*)(ws + 16777216);                // off1 out, 8+8 MiB
  _Float16* o1L = (_Float16*)(ws + 25165824);
  _Float16* w1H = (_Float16*)(ws + 33554432);                // off1/off2 weight tables
  _Float16* w1L = w1H + 18432;
  _Float16* w2H = w1L + 18432;
  _Float16* w2L = w2H + 9216;
  // outside warp region:
  _Float16* kH  = (_Float16*)(ws + 150994944);               // key pack, 8+8 MiB
  _Float16* kL  = (_Float16*)(ws + 159383552);
  _Float16* o2H = (_Float16*)(ws + 167772160);               // off2 out, 8+8 MiB
  _Float16* o2L = (_Float16*)(ws + 176160768);
  _Float16* wdH = (_Float16*)(ws + 184549376);               // dcn tables (165888 each)
  _Float16* wdL = wdH + 165888;                              // ends 185,212,928
  // post-dcn (K/off2/dcW regions dead):
  int*      idxb = (int*)(ws + 150994944);                   // 0.5 MiB
  _Float16* kwH  = (_Float16*)(ws + 159383552);              // selconv out, 8+8 MiB
  _Float16* kwL  = (_Float16*)(ws + 167772160);
  _Float16* twB  = (_Float16*)(ws + 176160768);              // tail weight tables
  _Float16* t1H_w = twB,            *t1L_w = twB + 18432;    // 9216 each
  _Float16* t3H_w = twB + 36864,    *t3L_w = twB + 184320;   // 147456 each
  _Float16* t5H_w = twB + 331776,   *t5L_w = twB + 341          * 1024 / 2;  // see below
  t5H_w = twB + 331776; t5L_w = t5H_w + 9216;
  // tail activations inside dead warp region:
  float*    y1  = (float*)(ws);                              // t1 out NHWC f32 [2,HW,32], 16 MiB
  _Float16* t2H = (_Float16*)(ws + 16777216);                // 32 MiB
  _Float16* t2L = (_Float16*)(ws + 50331648);                // 32 MiB
  float*    y3  = (float*)(ws + 83886080);                   // t3 out NHWC f32 [2,HW,128], 64 MiB (ends 147.8MB... )
  float*    y3b = (float*)(ws + 83886080);                   // alias
  _Float16* t4H = (_Float16*)(ws);                           // 8 MiB (y1 dead)
  _Float16* t4L = (_Float16*)(ws + 8388608);
  float* out = (float*)d_out;

  dim3 blk(256);

  // pack network inputs to NHWC f16 hi/lo
  pack_k<32><<<dim3(256, 2), blk, 0, stream>>>(x, xH, xL);
  pack_k<32><<<dim3(256, 2), blk, 0, stream>>>(key, kH, kL);
  // phase-1 weight tables
  prep_w_k<<<dim3(72),  blk, 0, stream>>>(w_off1, w1H, w1L, 32, 64);
  prep_w_k<<<dim3(36),  blk, 0, stream>>>(w_off2, w2H, w2L, 32, 32);
  prep_w_k<<<dim3(648), blk, 0, stream>>>(w_dcn,  wdH, wdL, 288, 64);

  // off1 = lrelu(conv(concat(x,key)))  -> NHWC f16
  conv3x3_mfma_k<64, 1, 1><<<dim3(2, 4, 64), blk, 0, stream>>>(
      xH, xL, kH, kL, 32, w1H, w1L, b_off1, nullptr, o1H, o1L, 32);
  // off2 = lrelu(conv(off1))           -> NHWC f16
  conv3x3_mfma_k<32, 1, 1><<<dim3(2, 4, 64), blk, 0, stream>>>(
      o1H, o1L, o1H, o1L, 32, w2H, w2L, b_off2, nullptr, o2H, o2L, 32);
  // warp = conv(concat(key,off2))      -> NCHW f32 (exactness for corr/top-k path)
  conv3x3_mfma_k<64, 0, 0><<<dim3(18, 4, 64), blk, 0, stream>>>(
      kH, kL, o2H, o2L, 32, wdH, wdL, b_dcn, warp, nullptr, nullptr, 288);
  // corr + top-3
  corr_topk_k<<<dim3(256, 2), blk, 0, stream>>>(warp, x, idxb);
  // key_warp -> NHWC f16 (kwH/kwL)
  selconv_k<<<dim3(8, 32, 2), blk, 0, stream>>>(warp, idxb, w_sel, b_sel, kwH, kwL);

  // phase-2 weight tables (off2L region dead)
  prep_w_k<<<dim3(36),  blk, 0, stream>>>(w_t1, t1H_w, t1L_w, 32, 32);
  prep_w_k<<<dim3(576), blk, 0, stream>>>(w_t3, t3H_w, t3L_w, 128, 128);
  prep_w_k<<<dim3(36),  blk, 0, stream>>>(w_t5, t5H_w, t5L_w, 32, 32);

  // t1: conv3x3 (gelu) -> NHWC f32 y1
  conv3x3_mfma_k<32, 2, 2><<<dim3(2, 4, 64), blk, 0, stream>>>(
      kwH, kwL, kwH, kwL, 32, t1H_w, t1L_w, nullptr, y1, nullptr, nullptr, 32);
  // t2: 1x1 (gelu) -> NHWC f16
  conv1x1_nhwc_k<32, 16, 2><<<dim3(64, 2, 8), blk, 0, stream>>>(y1, w_t2, t2H, t2L, 128);
  // t3: conv3x3 (gelu) -> NHWC f32 y3
  conv3x3_mfma_k<128, 2, 2><<<dim3(8, 4, 64), blk, 0, stream>>>(
      t2H, t2L, t2H, t2L, 128, t3H_w, t3L_w, nullptr, y3b, nullptr, nullptr, 128);
  // t4: 1x1 (gelu) -> NHWC f16
  conv1x1_nhwc_k<128, 16, 2><<<dim3(64, 2, 2), blk, 0, stream>>>(y3, w_t4, t4H, t4L, 32);
  // t5: conv3x3 -> NCHW f32 final
  conv3x3_mfma_k<32, 0, 0><<<dim3(2, 4, 64), blk, 0, stream>>>(
      t4H, t4L, t4H, t4L, 32, t5H_w, t5L_w, nullptr, out, nullptr, nullptr, 32);
}

// Round 8
// 789.529 us; speedup vs baseline: 1.1713x; 1.1713x over previous
//
#include <hip/hip_runtime.h>
#include <math.h>

static constexpr int H = 256, W = 256, HW = H * W;

typedef __attribute__((ext_vector_type(8))) _Float16 half8v;  // 16B
typedef __attribute__((ext_vector_type(4))) _Float16 half4v;  // 8B
typedef __attribute__((ext_vector_type(4))) float  float4v;   // MFMA acc

// ---------- activations ----------
__device__ __forceinline__ float gelu_f(float v) {
  return 0.5f * v * (1.0f + erff(v * 0.70710678118654752440f));
}
template<int ACT>
__device__ __forceinline__ float apply_act(float v) {
  if constexpr (ACT == 1) return v >= 0.f ? v : 0.1f * v;   // LeakyReLU(0.1)
  if constexpr (ACT == 2) return gelu_f(v);
  return v;
}

// ---------- pack: NCHW f32 (C=32) -> chunked NHWC f16 hi + scaled lo ----------
template<int C>
__global__ __launch_bounds__(256)
void pack_k(const float* __restrict__ in, _Float16* __restrict__ hi, _Float16* __restrict__ lo)
{
  const int p = blockIdx.x * 256 + threadIdx.x;
  const int b = blockIdx.y;
  const float* ip = in + (size_t)b * C * HW + p;
  __attribute__((aligned(16))) _Float16 hv[C], lv[C];
  #pragma unroll
  for (int c = 0; c < C; ++c) {
    float v = ip[(size_t)c * HW];
    _Float16 h = (_Float16)v;
    hv[c] = h;
    lv[c] = (_Float16)((v - (float)h) * 2048.0f);
  }
  size_t ob = ((size_t)b * HW + p) * C;
  #pragma unroll
  for (int j = 0; j < C / 8; ++j) {
    *(half8v*)&hi[ob + j * 8] = *(half8v*)&hv[j * 8];
    *(half8v*)&lo[ob + j * 8] = *(half8v*)&lv[j * 8];
  }
}

// ---------- weight prep: [OC][CIN][3][3] f32 -> [tap][OC][CIN] f16 hi + scaled lo ----------
__global__ __launch_bounds__(256)
void prep_w_k(const float* __restrict__ w, _Float16* __restrict__ hi,
              _Float16* __restrict__ lo, int OC, int CIN)
{
  int tid = blockIdx.x * 256 + threadIdx.x;
  if (tid >= OC * CIN * 9) return;
  int ci = tid % CIN; int r = tid / CIN; int oc = r % OC; int tap = r / OC;
  float v = w[((size_t)oc * CIN + ci) * 9 + tap];
  _Float16 h = (_Float16)v;
  hi[tid] = h;
  lo[tid] = (_Float16)((v - (float)h) * 2048.0f);
}

// ---------- 3x3 conv, f16 MFMA split-3; chunked-NHWC [B][C/32][H][W][32] f16 hi/lo input ----------
// OMODE: 0 = NCHW f32 out, 1 = NHWC f16 hi/lo out (OC=32 only), 2 = NHWC f32 out.
// Channels [0,cin0) from (iH0,iL0), rest from (iH1,iL1); cin0 % 32 == 0.
// LDS B-tile: [6 rows][66 px][8 granules x 16B] with XOR swizzle g^(px&7):
//   record stride 128B; coalesced staging writes; 2-way-max read/write conflicts.
// MFMA 16x16x32 f16 (HW-verified r5-r7): A row=l&15 (oc), k=(l>>4)*8+j;
//   B col=l&15 (px); D col=l&15 (px), row=(l>>4)*4+reg (oc).
template<int CIN, int ACT, int OMODE>
__global__ __launch_bounds__(256)
void conv3x3_mfma_k(const _Float16* __restrict__ iH0, const _Float16* __restrict__ iL0,
                    const _Float16* __restrict__ iH1, const _Float16* __restrict__ iL1, int cin0,
                    const _Float16* __restrict__ wHi, const _Float16* __restrict__ wLo,
                    const float* __restrict__ bias,
                    float* __restrict__ outF, _Float16* __restrict__ oH, _Float16* __restrict__ oL,
                    int OC)
{
  __shared__ _Float16 sB[6 * 66 * 64];   // 50,688 B -> 3 blocks/CU

  const int l  = threadIdx.x & 63;
  const int wv = threadIdx.x >> 6;
  const int nOc = OC >> 5;
  const int b   = blockIdx.x / nOc;
  const int oc0 = (blockIdx.x % nOc) * 32;
  const int x0  = blockIdx.y * 64;
  const int y0  = blockIdx.z * 4;

  float4v accP[2][4], accQ[2][4];
  #pragma unroll
  for (int of = 0; of < 2; ++of)
    #pragma unroll
    for (int f = 0; f < 4; ++f) {
      accP[of][f] = (float4v){0.f, 0.f, 0.f, 0.f};
      accQ[of][f] = (float4v){0.f, 0.f, 0.f, 0.f};
    }

  const int k8  = (l >> 4) * 8;
  const int ocl = l & 15;
  // staging lane roles: px-quad mapping (coalesced 16B loads)
  const int sq  = l & 3;          // ci granule within chunk-half
  const int spx = l >> 2;         // px offset within 16-px subtile

  #pragma unroll 1
  for (int cc = 0; cc < CIN; cc += 32) {
    // uniform chunk base resolution
    const _Float16 *cbH, *cbL;
    if (cc < cin0) {
      size_t o = (size_t)(b * (cin0 >> 5) + (cc >> 5)) * HW * 32;
      cbH = iH0 + o; cbL = iL0 + o;
    } else {
      size_t o = (size_t)(b * ((CIN - cin0) >> 5) + ((cc - cin0) >> 5)) * HW * 32;
      cbH = iH1 + o; cbL = iL1 + o;
    }
    __syncthreads();
    // ---- stage: 60 wave-tasks = 6 rows x {hi,lo} x 5 px-subtiles ----
    #pragma unroll 2
    for (int t = wv; t < 60; t += 4) {
      int r = t / 10; int rem = t - r * 10; int bsel = rem / 5; int s = rem - bsel * 5;
      const _Float16* src = bsel ? cbL : cbH;
      int gy = y0 + r - 1;
      bool vy = (gy >= 0) && (gy < H);
      int gyc = gy < 0 ? 0 : (gy >= H ? H - 1 : gy);
      int pxl = s * 16 + spx;                    // s=4: px 64,65 (lanes 0-7)
      bool lact = (s < 4) || (l < 8);
      int gx = x0 + pxl - 1;
      bool vx = (gx >= 0) && (gx < W);
      int gxc = gx < 0 ? 0 : (gx >= W ? W - 1 : gx);
      half8v v;
      #pragma unroll
      for (int i = 0; i < 8; ++i) v[i] = (_Float16)0;
      if (lact && vy && vx)
        v = *(const half8v*)&src[((size_t)gyc * W + gxc) * 32 + sq * 8];
      int cls = (sq + (bsel ? 4 : 0)) ^ (pxl & 7);
      if (lact)
        *(half8v*)&sB[(r * 66 + pxl) * 64 + cls * 8] = v;
    }
    __syncthreads();

    // ---- tap loop, depth-2 pipelined weight loads (named regs, no dyn idx) ----
    half8v ah0, ah1, aq0, aq1, nh0, nh1, nq0, nq1;
    {
      const _Float16* hp = wHi + ((size_t)(0 * OC) + oc0 + ocl) * CIN + cc + k8;
      const _Float16* lp = wLo + ((size_t)(0 * OC) + oc0 + ocl) * CIN + cc + k8;
      ah0 = *(const half8v*)hp;
      ah1 = *(const half8v*)(hp + (size_t)16 * CIN);
      aq0 = *(const half8v*)lp;
      aq1 = *(const half8v*)(lp + (size_t)16 * CIN);
    }
    #pragma unroll 1
    for (int tap = 0; tap < 9; ++tap) {
      if (tap < 8) {
        const _Float16* hp = wHi + ((size_t)((tap + 1) * OC) + oc0 + ocl) * CIN + cc + k8;
        const _Float16* lp = wLo + ((size_t)((tap + 1) * OC) + oc0 + ocl) * CIN + cc + k8;
        nh0 = *(const half8v*)hp;
        nh1 = *(const half8v*)(hp + (size_t)16 * CIN);
        nq0 = *(const half8v*)lp;
        nq1 = *(const half8v*)(lp + (size_t)16 * CIN);
      }
      const int dy = tap / 3, dx = tap - 3 * (tap / 3);
      const int px = ocl + dx;
      const int rbase = ((wv + dy) * 66 + px) * 64;
      const int clsH = (l >> 4) ^ (px & 7);
      const int clsQ = ((l >> 4) + 4) ^ (px & 7);
      #pragma unroll
      for (int f = 0; f < 4; ++f) {
        half8v bh = *(const half8v*)&sB[rbase + f * 1024 + clsH * 8];
        half8v bq = *(const half8v*)&sB[rbase + f * 1024 + clsQ * 8];
        accP[0][f] = __builtin_amdgcn_mfma_f32_16x16x32_f16(ah0, bh, accP[0][f], 0, 0, 0);
        accQ[0][f] = __builtin_amdgcn_mfma_f32_16x16x32_f16(ah0, bq, accQ[0][f], 0, 0, 0);
        accQ[0][f] = __builtin_amdgcn_mfma_f32_16x16x32_f16(aq0, bh, accQ[0][f], 0, 0, 0);
        accP[1][f] = __builtin_amdgcn_mfma_f32_16x16x32_f16(ah1, bh, accP[1][f], 0, 0, 0);
        accQ[1][f] = __builtin_amdgcn_mfma_f32_16x16x32_f16(ah1, bq, accQ[1][f], 0, 0, 0);
        accQ[1][f] = __builtin_amdgcn_mfma_f32_16x16x32_f16(aq1, bh, accQ[1][f], 0, 0, 0);
      }
      ah0 = nh0; ah1 = nh1; aq0 = nq0; aq1 = nq1;
    }
  }

  // ---- epilogue: D col=l&15 (px), row=(l>>4)*4+reg (oc) ----
  #pragma unroll
  for (int of = 0; of < 2; ++of)
    #pragma unroll
    for (int f = 0; f < 4; ++f) {
      const int px  = x0 + f * 16 + ocl;
      const int occ = oc0 + of * 16 + (l >> 4) * 4;
      if constexpr (OMODE == 0) {
        #pragma unroll
        for (int r = 0; r < 4; ++r) {
          float bv = bias ? bias[occ + r] : 0.f;
          float vv = accP[of][f][r] + accQ[of][f][r] * (1.0f / 2048.0f) + bv;
          outF[((size_t)(b * OC + occ + r) * H + (y0 + wv)) * W + px] = apply_act<ACT>(vv);
        }
      } else if constexpr (OMODE == 1) {
        __attribute__((aligned(8))) _Float16 hv[4], lv[4];
        #pragma unroll
        for (int r = 0; r < 4; ++r) {
          float bv = bias ? bias[occ + r] : 0.f;
          float vv = apply_act<ACT>(accP[of][f][r] + accQ[of][f][r] * (1.0f / 2048.0f) + bv);
          _Float16 h = (_Float16)vv;
          hv[r] = h;
          lv[r] = (_Float16)((vv - (float)h) * 2048.0f);
        }
        size_t ob = ((size_t)b * HW + (size_t)(y0 + wv) * W + px) * OC + occ;
        *(half4v*)&oH[ob] = *(half4v*)&hv[0];
        *(half4v*)&oL[ob] = *(half4v*)&lv[0];
      } else {
        float4 v4;
        #pragma unroll
        for (int r = 0; r < 4; ++r) {
          float bv = bias ? bias[occ + r] : 0.f;
          ((float*)&v4)[r] = apply_act<ACT>(accP[of][f][r] + accQ[of][f][r] * (1.0f / 2048.0f) + bv);
        }
        *(float4*)&outF[((size_t)b * HW + (size_t)(y0 + wv) * W + px) * OC + occ] = v4;
      }
    }
}

// ---------- 1x1 conv: NHWC f32 in -> chunked NHWC f16 hi/lo out ----------
template<int CIN, int OCB, int ACT>
__global__ __launch_bounds__(256)
void conv1x1_nhwc_k(const float* __restrict__ in, const float* __restrict__ w,
                    _Float16* __restrict__ oH, _Float16* __restrict__ oL, int OC)
{
  __shared__ __align__(16) float sW[OCB][CIN];
  const int b   = blockIdx.y;
  const int oc0 = blockIdx.z * OCB;
  for (int t = threadIdx.x; t < OCB * CIN; t += 256)
    sW[t / CIN][t % CIN] = w[(size_t)(oc0 + t / CIN) * CIN + (t % CIN)];
  __syncthreads();

  const int pb = blockIdx.x * 1024 + threadIdx.x;    // 4 px at stride 256
  float acc[OCB][4];
  #pragma unroll
  for (int o = 0; o < OCB; ++o)
    #pragma unroll
    for (int i = 0; i < 4; ++i) acc[o][i] = 0.f;

  #pragma unroll 1
  for (int c0 = 0; c0 < CIN; c0 += 8) {
    float v[4][8];
    #pragma unroll
    for (int i = 0; i < 4; ++i) {
      const float* ip = in + ((size_t)b * HW + pb + i * 256) * CIN + c0;
      float4 a = *(const float4*)ip;
      float4 c = *(const float4*)(ip + 4);
      v[i][0]=a.x; v[i][1]=a.y; v[i][2]=a.z; v[i][3]=a.w;
      v[i][4]=c.x; v[i][5]=c.y; v[i][6]=c.z; v[i][7]=c.w;
    }
    #pragma unroll
    for (int o = 0; o < OCB; ++o) {
      const float4 w0 = *(const float4*)&sW[o][c0];
      const float4 w1 = *(const float4*)&sW[o][c0 + 4];
      #pragma unroll
      for (int i = 0; i < 4; ++i) {
        acc[o][i] += v[i][0]*w0.x + v[i][1]*w0.y + v[i][2]*w0.z + v[i][3]*w0.w
                   + v[i][4]*w1.x + v[i][5]*w1.y + v[i][6]*w1.z + v[i][7]*w1.w;
      }
    }
  }
  #pragma unroll
  for (int i = 0; i < 4; ++i) {
    __attribute__((aligned(16))) _Float16 hv[OCB], lv[OCB];
    #pragma unroll
    for (int o = 0; o < OCB; ++o) {
      float vv = apply_act<ACT>(acc[o][i]);
      _Float16 h = (_Float16)vv;
      hv[o] = h;
      lv[o] = (_Float16)((vv - (float)h) * 2048.0f);
    }
    // chunked store: [B][OC/32][HW][32]
    size_t ob = ((size_t)(b * (OC >> 5) + (oc0 >> 5)) * HW + pb + i * 256) * 32 + (oc0 & 31);
    #pragma unroll
    for (int j = 0; j < OCB / 8; ++j) {
      *(half8v*)&oH[ob + j * 8] = *(half8v*)&hv[j * 8];
      *(half8v*)&oL[ob + j * 8] = *(half8v*)&lv[j * 8];
    }
  }
}

// ---------- corr + top-3 (jax tie-break: lower index wins); warp NCHW f32 ----------
__global__ __launch_bounds__(256)
void corr_topk_k(const float* __restrict__ warp, const float* __restrict__ x,
                 int* __restrict__ idxo)
{
  const int p = blockIdx.x * 256 + threadIdx.x;
  const int b = blockIdx.y;
  float corr[9];
  #pragma unroll
  for (int o = 0; o < 9; ++o) corr[o] = 0.f;
  #pragma unroll 2
  for (int c = 0; c < 32; ++c) {
    float xv = x[((size_t)b * 32 + c) * HW + p];
    const float* wp = warp + ((size_t)b * 288 + (size_t)c * 9) * HW + p;
    #pragma unroll
    for (int o = 0; o < 9; ++o) corr[o] += wp[(size_t)o * HW] * xv;
  }
  unsigned mask = 0;
  int packed = 0;
  #pragma unroll
  for (int t = 0; t < 3; ++t) {
    float best = -INFINITY; int bi = 0;
    #pragma unroll
    for (int o = 0; o < 9; ++o) {
      bool take = (((mask >> o) & 1u) == 0u) && (corr[o] > best);
      best = take ? corr[o] : best;
      bi   = take ? o       : bi;
    }
    mask   |= 1u << bi;
    packed |= bi << (4 * t);
  }
  idxo[(size_t)b * HW + p] = packed;
}

// ---------- gather selected warps + 3x3 conv with w_sel; out 32-ch NHWC f16 hi/lo ----------
__global__ __launch_bounds__(256)
void selconv_k(const float* __restrict__ warp, const int* __restrict__ idxp,
               const float* __restrict__ wsel, const float* __restrict__ bsel,
               _Float16* __restrict__ oH, _Float16* __restrict__ oL)
{
  const int tx = threadIdx.x & 31, ty = threadIdx.x >> 5;
  const int px = blockIdx.x * 32 + tx;
  const int py = blockIdx.y * 8 + ty;
  const int b  = blockIdx.z;

  int  nidx[9];
  bool nval[9];
  int  qoff[9];
  #pragma unroll
  for (int kh = 0; kh < 3; ++kh)
    #pragma unroll
    for (int kw = 0; kw < 3; ++kw) {
      int k = kh * 3 + kw;
      int qy = py + kh - 1, qx = px + kw - 1;
      nval[k] = (qy >= 0 && qy < H && qx >= 0 && qx < W);
      qoff[k] = qy * W + qx;
      nidx[k] = nval[k] ? idxp[(size_t)b * HW + qoff[k]] : 0;
    }

  float ws27[27];
  #pragma unroll
  for (int i = 0; i < 27; ++i) ws27[i] = wsel[i];
  const float bs = bsel[0];

  float arr[32];
  #pragma unroll 1
  for (int c = 0; c < 32; ++c) {
    float acc = bs;
    const float* wb = warp + ((size_t)b * 288 + (size_t)c * 9) * HW;
    #pragma unroll
    for (int k = 0; k < 9; ++k) {
      if (nval[k]) {
        int pk = nidx[k];
        #pragma unroll
        for (int t = 0; t < 3; ++t) {
          int o = (pk >> (4 * t)) & 15;
          acc += ws27[t * 9 + k] * wb[(size_t)o * HW + qoff[k]];
        }
      }
    }
    arr[c] = acc;
  }

  __attribute__((aligned(16))) _Float16 hv[32], lv[32];
  #pragma unroll
  for (int c = 0; c < 32; ++c) {
    _Float16 h = (_Float16)arr[c];
    hv[c] = h;
    lv[c] = (_Float16)((arr[c] - (float)h) * 2048.0f);
  }
  size_t ob = ((size_t)b * HW + (size_t)py * W + px) * 32;
  #pragma unroll
  for (int j = 0; j < 4; ++j) {
    *(half8v*)&oH[ob + j * 8] = *(half8v*)&hv[j * 8];
    *(half8v*)&oL[ob + j * 8] = *(half8v*)&lv[j * 8];
  }
}

// ---------- launch ----------
extern "C" void kernel_launch(void* const* d_in, const int* in_sizes, int n_in,
                              void* d_out, int out_size, void* d_ws, size_t ws_size,
                              hipStream_t stream) {
  const float* x      = (const float*)d_in[0];
  const float* key    = (const float*)d_in[1];
  const float* w_off1 = (const float*)d_in[2];
  const float* b_off1 = (const float*)d_in[3];
  const float* w_off2 = (const float*)d_in[4];
  const float* b_off2 = (const float*)d_in[5];
  const float* w_dcn  = (const float*)d_in[6];
  const float* b_dcn  = (const float*)d_in[7];
  const float* w_sel  = (const float*)d_in[8];
  const float* b_sel  = (const float*)d_in[9];
  const float* w_t1   = (const float*)d_in[10];
  const float* w_t2   = (const float*)d_in[11];
  const float* w_t3   = (const float*)d_in[12];
  const float* w_t4   = (const float*)d_in[13];
  const float* w_t5   = (const float*)d_in[14];

  // ---- workspace layout (peak 185.2 MB; proven safe in r5-r7) ----
  char* ws = (char*)d_ws;
  float* warp = (float*)(ws);                                // [2,288,HW] f32 NCHW, 144 MiB
  // pre-dcn scratch inside warp region (dead before dcn writes):
  _Float16* xH  = (_Float16*)(ws);                           // 8 MiB
  _Float16* xL  = (_Float16*)(ws + 8388608);
  _Float16* o1H = (_Float16*)(ws + 16777216);                // off1 out, 8+8 MiB
  _Float16* o1L = (_Float16*)(ws + 25165824);
  _Float16* w1H = (_Float16*)(ws + 33554432);                // off1/off2 weight tables
  _Float16* w1L = w1H + 18432;
  _Float16* w2H = w1L + 18432;
  _Float16* w2L = w2H + 9216;
  // outside warp region:
  _Float16* kH  = (_Float16*)(ws + 150994944);               // key pack, 8+8 MiB
  _Float16* kL  = (_Float16*)(ws + 159383552);
  _Float16* o2H = (_Float16*)(ws + 167772160);               // off2 out, 8+8 MiB
  _Float16* o2L = (_Float16*)(ws + 176160768);
  _Float16* wdH = (_Float16*)(ws + 184549376);               // dcn tables (165888 each)
  _Float16* wdL = wdH + 165888;                              // ends ~185.2 MB
  // post-dcn (kH/kL/o2H/o2L/wd regions become dead in stages):
  int*      idxb = (int*)(ws + 150994944);                   // 0.5 MiB (over kH, dead)
  _Float16* kwH  = (_Float16*)(ws + 159383552);              // selconv out (over kL)
  _Float16* kwL  = (_Float16*)(ws + 167772160);              //              (over o2H)
  _Float16* twB  = (_Float16*)(ws + 176160768);              // tail tables (over o2L)
  _Float16* t1H_w = twB;
  _Float16* t1L_w = twB + 9216;
  _Float16* t3H_w = twB + 18432;
  _Float16* t3L_w = twB + 165888;
  _Float16* t5H_w = twB + 313344;
  _Float16* t5L_w = twB + 322560;                            // ends +663KB, < 8.3MB hole
  // tail activations inside dead warp region:
  float*    y1  = (float*)(ws);                              // t1 out NHWC f32 [2,HW,32], 16 MiB
  _Float16* t2H = (_Float16*)(ws + 16777216);                // chunked [2,4,HW,32], 32 MiB
  _Float16* t2L = (_Float16*)(ws + 50331648);                // 32 MiB
  float*    y3  = (float*)(ws + 83886080);                   // t3 out NHWC f32 [2,HW,128], 64 MiB
  _Float16* t4H = (_Float16*)(ws);                           // 8 MiB (y1 dead by then)
  _Float16* t4L = (_Float16*)(ws + 8388608);
  float* out = (float*)d_out;

  dim3 blk(256);

  // pack network inputs -> chunked f16 hi/lo (C=32: identical to NHWC)
  pack_k<32><<<dim3(256, 2), blk, 0, stream>>>(x, xH, xL);
  pack_k<32><<<dim3(256, 2), blk, 0, stream>>>(key, kH, kL);
  // phase-1 weight tables
  prep_w_k<<<dim3(72),  blk, 0, stream>>>(w_off1, w1H, w1L, 32, 64);
  prep_w_k<<<dim3(36),  blk, 0, stream>>>(w_off2, w2H, w2L, 32, 32);
  prep_w_k<<<dim3(648), blk, 0, stream>>>(w_dcn,  wdH, wdL, 288, 64);

  // off1 = lrelu(conv(concat(x,key)))  -> f16 hi/lo
  conv3x3_mfma_k<64, 1, 1><<<dim3(2, 4, 64), blk, 0, stream>>>(
      xH, xL, kH, kL, 32, w1H, w1L, b_off1, nullptr, o1H, o1L, 32);
  // off2 = lrelu(conv(off1))           -> f16 hi/lo
  conv3x3_mfma_k<32, 1, 1><<<dim3(2, 4, 64), blk, 0, stream>>>(
      o1H, o1L, o1H, o1L, 32, w2H, w2L, b_off2, nullptr, o2H, o2L, 32);
  // warp = conv(concat(key,off2))      -> NCHW f32 (feeds exact corr/top-k)
  conv3x3_mfma_k<64, 0, 0><<<dim3(18, 4, 64), blk, 0, stream>>>(
      kH, kL, o2H, o2L, 32, wdH, wdL, b_dcn, warp, nullptr, nullptr, 288);
  // corr + top-3
  corr_topk_k<<<dim3(256, 2), blk, 0, stream>>>(warp, x, idxb);
  // key_warp -> f16 hi/lo (kwH/kwL)
  selconv_k<<<dim3(8, 32, 2), blk, 0, stream>>>(warp, idxb, w_sel, b_sel, kwH, kwL);

  // phase-2 weight tables
  prep_w_k<<<dim3(36),  blk, 0, stream>>>(w_t1, t1H_w, t1L_w, 32, 32);
  prep_w_k<<<dim3(576), blk, 0, stream>>>(w_t3, t3H_w, t3L_w, 128, 128);
  prep_w_k<<<dim3(36),  blk, 0, stream>>>(w_t5, t5H_w, t5L_w, 32, 32);

  // t1: conv3x3 (gelu) -> NHWC f32 y1
  conv3x3_mfma_k<32, 2, 2><<<dim3(2, 4, 64), blk, 0, stream>>>(
      kwH, kwL, kwH, kwL, 32, t1H_w, t1L_w, nullptr, y1, nullptr, nullptr, 32);
  // t2: 1x1 (gelu) -> chunked f16 [2,4,HW,32]
  conv1x1_nhwc_k<32, 16, 2><<<dim3(64, 2, 8), blk, 0, stream>>>(y1, w_t2, t2H, t2L, 128);
  // t3: conv3x3 (gelu) -> NHWC f32 y3
  conv3x3_mfma_k<128, 2, 2><<<dim3(8, 4, 64), blk, 0, stream>>>(
      t2H, t2L, t2H, t2L, 128, t3H_w, t3L_w, nullptr, y3, nullptr, nullptr, 128);
  // t4: 1x1 (gelu) -> f16 hi/lo
  conv1x1_nhwc_k<128, 16, 2><<<dim3(64, 2, 2), blk, 0, stream>>>(y3, w_t4, t4H, t4L, 32);
  // t5: conv3x3 -> NCHW f32 final
  conv3x3_mfma_k<32, 0, 0><<<dim3(2, 4, 64), blk, 0, stream>>>(
      t4H, t4L, t4H, t4L, 32, t5H_w, t5L_w, nullptr, out, nullptr, nullptr, 32);
}